// Round 2
// baseline (1644.200 us; speedup 1.0000x reference)
//
#include <hip/hip_runtime.h>
#include <hip/hip_bf16.h>

#define BB 1024
#define NN 32
#define SUD 8
#define HD 64
#define NCD 4
#define ED 992      // NN*(NN-1)
#define NITER 5

// ---- fp32 weight workspace layout (element offsets into d_ws) ----
#define O_W2AT 0        // 18 x 64   W2aT[su][f] = W2a[f][su]
#define O_B2A  1152     // 64
#define O_W2B  1216     // 32 x 64   row-major as given
#define O_B2B  3264     // 32
#define O_W2CT 3296     // 32 x 8    W2cT[o][su] = W2c[su][o]
#define O_B2C  3552     // 8
#define O_WIHT 3560     // 10 x 192  WihT[k][o]
#define O_BIH  5480     // 192
#define O_WHHT 5672     // 64 x 192  WhhT[k][o]
#define O_BHH  17960    // 192
#define O_W4T  18152    // 64 x 8    W4T[k][su]
#define O_B4   18664    // 8
#define O_W3AT 18672    // 8 x 64    W3aT[k][f]
#define O_B3A  19184    // 64
#define O_W3BT 19248    // 64 x 32   W3bT[k][f]
#define O_B3B  21296    // 32
#define O_W3CT 21328    // 32 x 4    W3cT[k][c]
#define O_B3C  21456    // 4
#define O_W1AT 21460    // 3 x 8     W1aT[c][su]
#define O_B1A  21484    // 8
#define W_TOTAL 21492   // floats (= 85,968 bytes in d_ws)

typedef const float* fwp;

// Transpose all weights into the layouts the main kernel wants. One elem/thread.
__global__ void prep_weights(fwp W2a, fwp b2a, fwp W2b, fwp b2b, fwp W2c, fwp b2c,
                             fwp Wih, fwp bih, fwp Whh, fwp bhh,
                             fwp W3a, fwp b3a, fwp W3b, fwp b3b, fwp W3c, fwp b3c,
                             fwp W4, fwp b4, fwp W1a, fwp b1a, float* __restrict__ ws) {
  int idx = blockIdx.x * 256 + threadIdx.x;
  if (idx >= W_TOTAL) return;
  float v;
  if (idx < O_B2A)       { int p = idx;          int su = p / 64, f = p % 64;   v = W2a[f * 18 + su]; }
  else if (idx < O_W2B)  { v = b2a[idx - O_B2A]; }
  else if (idx < O_B2B)  { v = W2b[idx - O_W2B]; }
  else if (idx < O_W2CT) { v = b2b[idx - O_B2B]; }
  else if (idx < O_B2C)  { int p = idx - O_W2CT; int o = p / 8, su = p % 8;     v = W2c[su * 32 + o]; }
  else if (idx < O_WIHT) { v = b2c[idx - O_B2C]; }
  else if (idx < O_BIH)  { int p = idx - O_WIHT; int k = p / 192, o = p % 192;  v = Wih[o * 10 + k]; }
  else if (idx < O_WHHT) { v = bih[idx - O_BIH]; }
  else if (idx < O_BHH)  { int p = idx - O_WHHT; int k = p / 192, o = p % 192;  v = Whh[o * 64 + k]; }
  else if (idx < O_W4T)  { v = bhh[idx - O_BHH]; }
  else if (idx < O_B4)   { int p = idx - O_W4T;  int k = p / 8, su = p % 8;     v = W4[su * 64 + k]; }
  else if (idx < O_W3AT) { v = b4[idx - O_B4]; }
  else if (idx < O_B3A)  { int p = idx - O_W3AT; int k = p / 64, f = p % 64;    v = W3a[f * 8 + k]; }
  else if (idx < O_W3BT) { v = b3a[idx - O_B3A]; }
  else if (idx < O_B3B)  { int p = idx - O_W3BT; int k = p / 32, f = p % 32;    v = W3b[f * 64 + k]; }
  else if (idx < O_W3CT) { v = b3b[idx - O_B3B]; }
  else if (idx < O_B3C)  { int p = idx - O_W3CT; int k = p / 4, c = p % 4;      v = W3c[c * 32 + k]; }
  else if (idx < O_W1AT) { v = b3c[idx - O_B3C]; }
  else if (idx < O_B1A)  { int p = idx - O_W1AT; int c = p / 8, su = p % 8;     v = W1a[su * 3 + c]; }
  else                   { v = b1a[idx - O_B1A]; }
  ws[idx] = v;
}

// One block per batch sample. Entire 5-iteration recurrence lives in LDS/regs.
__global__ __launch_bounds__(256, 3) void gnn_fused(
    const float* __restrict__ read_gru_in,
    const float* __restrict__ gru_init,
    const float* __restrict__ feat,
    const float* __restrict__ edge_w,
    const float* __restrict__ noise_in,
    const float* __restrict__ xhat,
    const float* __restrict__ vep,
    const int* __restrict__ gnn_iter_p,
    const float* __restrict__ ws,
    float* __restrict__ out)
{
  __shared__ float  sA1[NN * 65];    // A1[n][f]   (pad 65: conflict-free)
  __shared__ float  sA2[NN * 65];    // A2[n][f]
  __shared__ float  sH [NN * 65];    // gru_hidden[n][k]
  __shared__ float  sNodes[NN * 9];  // init_nodes / read_gru [n][su]
  __shared__ float  sSum[NN * 8];    // sum_msgs[n][su]
  __shared__ float  sPart[256 * 9];  // per-thread partial sums (pad 9)
  __shared__ float  sEw[ED];         // per-sample edge weights
  __shared__ float2 sCW[64];         // (c1[f] = b2a+noise*W2a[:,17], wew[f] = W2a[:,16])
  __shared__ float  sX[NN];
  __shared__ float  sV[NN];

  const int b = blockIdx.x;
  const int t = threadIdx.x;

  // ---- load per-sample inputs ----
  float noi = noise_in[b];
  for (int e = t; e < ED; e += 256) sEw[e] = edge_w[b * ED + e];
  if (t < NN) { sX[t] = xhat[b * NN + t]; sV[t] = vep[b * NN + t]; }
  if (t < 64) {
    float c1 = ws[O_B2A + t] + noi * ws[O_W2AT + 17 * 64 + t];
    float wewf = ws[O_W2AT + 16 * 64 + t];
    sCW[t] = make_float2(c1, wewf);
  }
#pragma unroll
  for (int i = 0; i < 8; ++i) {
    int p = t + 256 * i;
    sH[(p >> 6) * 65 + (p & 63)] = gru_init[b * (NN * HD) + p];
  }
  const int git = gnn_iter_p[0];

  for (int it = 0; it < NITER; ++it) {
    // ---- init_nodes ----
    if (it == 0) {
      int n = t >> 3, su = t & 7;
      float acc;
      if (git == 0) {
        acc = ws[O_B1A + su];
#pragma unroll
        for (int c = 0; c < 3; ++c)
          acc += ws[O_W1AT + c * 8 + su] * feat[b * (NN * 3) + n * 3 + c];
      } else {
        acc = read_gru_in[b * (NN * SUD) + t];
      }
      sNodes[n * 9 + su] = acc;
    }
    __syncthreads();

    // ---- A1[n] = W2a[:,0:8] @ nodes[n],  A2[n] = W2a[:,8:16] @ nodes[n] ----
#pragma unroll
    for (int i = 0; i < 8; ++i) {
      int p = t + 256 * i;
      int n = p >> 6, f = p & 63;            // n is wave-uniform, f = lane
      float a1 = 0.f, a2 = 0.f;
#pragma unroll
      for (int su = 0; su < 8; ++su) {
        float nv = sNodes[n * 9 + su];       // LDS broadcast
        a1 += ws[O_W2AT + su * 64 + f] * nv; // coalesced fp32
        a2 += ws[O_W2AT + (8 + su) * 64 + f] * nv;
      }
      sA1[n * 65 + f] = a1;
      sA2[n * 65 + f] = a2;
    }
    __syncthreads();

    // ---- edge MLP, fused layers b+c, per-thread edges ----
    {
      int jj = t >> 3, ii = t & 7;           // dest node jj, sub-lane ii
      float msum[8];
#pragma unroll
      for (int s = 0; s < 8; ++s) msum[s] = 0.f;
      for (int k = ii; k < 31; k += 8) {
        int a = k + (k >= jj ? 1 : 0);       // temp_a index
        float ewv = sEw[jj * 31 + k];
        float m1[64];
#pragma unroll
        for (int f = 0; f < 64; ++f) {
          float2 cw = sCW[f];                // broadcast b64
          float v = sA1[a * 65 + f] + sA2[jj * 65 + f] + cw.x + ewv * cw.y;
          m1[f] = v > 0.f ? v : 0.f;
        }
        float m3[8];
#pragma unroll
        for (int s = 0; s < 8; ++s) m3[s] = ws[O_B2C + s];
        for (int o = 0; o < 32; ++o) {       // wave-uniform -> scalar loads
          const float* wrow = ws + O_W2B + o * 64;
          float c0 = 0.f, c1v = 0.f, c2 = 0.f, c3 = 0.f;
#pragma unroll
          for (int k2 = 0; k2 < 64; k2 += 4) {
            c0  += wrow[k2 + 0] * m1[k2 + 0];
            c1v += wrow[k2 + 1] * m1[k2 + 1];
            c2  += wrow[k2 + 2] * m1[k2 + 2];
            c3  += wrow[k2 + 3] * m1[k2 + 3];
          }
          float acc = ws[O_B2B + o] + ((c0 + c1v) + (c2 + c3));
          acc = acc > 0.f ? acc : 0.f;       // relu layer b
          const float* crow = ws + O_W2CT + o * 8;
#pragma unroll
          for (int s = 0; s < 8; ++s) m3[s] += crow[s] * acc;  // fused layer c
        }
#pragma unroll
        for (int s = 0; s < 8; ++s) { float v = m3[s]; msum[s] += (v > 0.f ? v : 0.f); } // relu layer c
      }
#pragma unroll
      for (int s = 0; s < 8; ++s) sPart[t * 9 + s] = msum[s];
    }
    __syncthreads();

    // ---- reduce 8 partials per node -> sum_msgs ----
    {
      int n = t >> 3, su = t & 7;
      float acc = 0.f;
#pragma unroll
      for (int i = 0; i < 8; ++i) acc += sPart[(n * 8 + i) * 9 + su];
      sSum[n * 8 + su] = acc;
    }
    __syncthreads();

    // ---- GRU: lane owns gate-column oo for 8 nodes ----
    {
      int oo = t & 63, wq = t >> 6;
      float ar[8], az[8], inx[8], hn[8];
      {
        float br  = ws[O_BIH + oo]        + ws[O_BHH + oo];
        float bz  = ws[O_BIH + 64 + oo]   + ws[O_BHH + 64 + oo];
        float bni = ws[O_BIH + 128 + oo];
        float bnh = ws[O_BHH + 128 + oo];
#pragma unroll
        for (int j = 0; j < 8; ++j) { ar[j] = br; az[j] = bz; inx[j] = bni; hn[j] = bnh; }
      }
#pragma unroll
      for (int k = 0; k < 8; ++k) {          // gi over sum_msgs
        float wr = ws[O_WIHT + k * 192 + oo];
        float wz = ws[O_WIHT + k * 192 + 64 + oo];
        float wn = ws[O_WIHT + k * 192 + 128 + oo];
#pragma unroll
        for (int j = 0; j < 8; ++j) {
          float g = sSum[(wq + 4 * j) * 8 + k];
          ar[j] += wr * g; az[j] += wz * g; inx[j] += wn * g;
        }
      }
      {                                      // gi over x_hat (k=8) and var (k=9)
        float wr = ws[O_WIHT + 8 * 192 + oo];
        float wz = ws[O_WIHT + 8 * 192 + 64 + oo];
        float wn = ws[O_WIHT + 8 * 192 + 128 + oo];
#pragma unroll
        for (int j = 0; j < 8; ++j) {
          float g = sX[wq + 4 * j];
          ar[j] += wr * g; az[j] += wz * g; inx[j] += wn * g;
        }
        wr = ws[O_WIHT + 9 * 192 + oo];
        wz = ws[O_WIHT + 9 * 192 + 64 + oo];
        wn = ws[O_WIHT + 9 * 192 + 128 + oo];
#pragma unroll
        for (int j = 0; j < 8; ++j) {
          float g = sV[wq + 4 * j];
          ar[j] += wr * g; az[j] += wz * g; inx[j] += wn * g;
        }
      }
#pragma unroll 4
      for (int k = 0; k < 64; ++k) {         // gh over hidden
        float wr = ws[O_WHHT + k * 192 + oo];
        float wz = ws[O_WHHT + k * 192 + 64 + oo];
        float wn = ws[O_WHHT + k * 192 + 128 + oo];
#pragma unroll
        for (int j = 0; j < 8; ++j) {
          float hk = sH[(wq + 4 * j) * 65 + k];  // broadcast
          ar[j] += wr * hk; az[j] += wz * hk; hn[j] += wn * hk;
        }
      }
      float hnew[8];
#pragma unroll
      for (int j = 0; j < 8; ++j) {
        int n = wq + 4 * j;
        float r = 1.f / (1.f + __expf(-ar[j]));
        float z = 1.f / (1.f + __expf(-az[j]));
        float cd = inx[j] + r * hn[j];
        float e2 = __expf(2.f * cd);
        float th = 1.f - 2.f / (e2 + 1.f);   // tanh(cd)
        hnew[j] = (1.f - z) * th + z * sH[n * 65 + oo];
      }
      __syncthreads();                        // all old-h reads done
#pragma unroll
      for (int j = 0; j < 8; ++j) sH[(wq + 4 * j) * 65 + oo] = hnew[j];
    }
    __syncthreads();

    // ---- read_gru = W4 @ h + b4 -> sNodes (next iter's init_nodes) ----
    {
      int n = t >> 3, su = t & 7;
      float c0 = 0.f, c1v = 0.f, c2 = 0.f, c3 = 0.f;
#pragma unroll
      for (int k = 0; k < 64; k += 4) {
        c0  += ws[O_W4T + (k + 0) * 8 + su] * sH[n * 65 + k + 0];
        c1v += ws[O_W4T + (k + 1) * 8 + su] * sH[n * 65 + k + 1];
        c2  += ws[O_W4T + (k + 2) * 8 + su] * sH[n * 65 + k + 2];
        c3  += ws[O_W4T + (k + 3) * 8 + su] * sH[n * 65 + k + 3];
      }
      sNodes[n * 9 + su] = ws[O_B4 + su] + ((c0 + c1v) + (c2 + c3));
    }
    __syncthreads();
  } // iterations

  // ---- head: q1 = read @ W3aT + b3a (32x64) -> reuse sA1 ----
#pragma unroll
  for (int i = 0; i < 8; ++i) {
    int p = t + 256 * i;
    int n = p >> 6, f = p & 63;
    float acc = ws[O_B3A + f];
#pragma unroll
    for (int k = 0; k < 8; ++k) acc += ws[O_W3AT + k * 64 + f] * sNodes[n * 9 + k];
    sA1[n * 65 + f] = acc;
  }
  __syncthreads();
  // q2 (32x32) -> reuse sA2 at stride 33
#pragma unroll
  for (int i = 0; i < 4; ++i) {
    int p = t + 256 * i;
    int n = p >> 5, f = p & 31;
    float c0 = 0.f, c1v = 0.f, c2 = 0.f, c3 = 0.f;
#pragma unroll
    for (int k = 0; k < 64; k += 4) {
      c0  += ws[O_W3BT + (k + 0) * 32 + f] * sA1[n * 65 + k + 0];
      c1v += ws[O_W3BT + (k + 1) * 32 + f] * sA1[n * 65 + k + 1];
      c2  += ws[O_W3BT + (k + 2) * 32 + f] * sA1[n * 65 + k + 2];
      c3  += ws[O_W3BT + (k + 3) * 32 + f] * sA1[n * 65 + k + 3];
    }
    sA2[n * 33 + f] = ws[O_B3B + f] + ((c0 + c1v) + (c2 + c3));
  }
  __syncthreads();
  // p_y_x (32x4) + store
  if (t < 128) {
    int n = t >> 2, c = t & 3;
    float acc = ws[O_B3C + c];
#pragma unroll
    for (int k = 0; k < 32; ++k) acc += ws[O_W3CT + k * 4 + c] * sA2[n * 33 + k];
    out[b * (NN * NCD) + t] = acc;
  }
  // read_gru out
  out[BB * NN * NCD + b * (NN * SUD) + t] = sNodes[(t >> 3) * 9 + (t & 7)];
  // gru_hidden out
#pragma unroll
  for (int i = 0; i < 8; ++i) {
    int p = t + 256 * i;
    out[BB * NN * NCD + BB * NN * SUD + b * (NN * HD) + p] =
        sH[(p >> 6) * 65 + (p & 63)];
  }
}

extern "C" void kernel_launch(void* const* d_in, const int* in_sizes, int n_in,
                              void* d_out, int out_size, void* d_ws, size_t ws_size,
                              hipStream_t stream) {
  typedef const float* F32;
  F32 read_gru = (F32)d_in[0];
  F32 gru_init = (F32)d_in[1];
  F32 feat     = (F32)d_in[2];
  F32 edge_w   = (F32)d_in[3];
  F32 noise    = (F32)d_in[4];
  F32 xh       = (F32)d_in[5];
  F32 vp       = (F32)d_in[6];
  F32 W1a = (F32)d_in[7];  F32 b1a = (F32)d_in[8];
  F32 W2a = (F32)d_in[9];  F32 b2a = (F32)d_in[10];
  F32 W2b = (F32)d_in[11]; F32 b2b = (F32)d_in[12];
  F32 W2c = (F32)d_in[13]; F32 b2c = (F32)d_in[14];
  F32 Wih = (F32)d_in[15]; F32 bih = (F32)d_in[16];
  F32 Whh = (F32)d_in[17]; F32 bhh = (F32)d_in[18];
  F32 W3a = (F32)d_in[19]; F32 b3a = (F32)d_in[20];
  F32 W3b = (F32)d_in[21]; F32 b3b = (F32)d_in[22];
  F32 W3c = (F32)d_in[23]; F32 b3c = (F32)d_in[24];
  F32 W4  = (F32)d_in[25]; F32 b4  = (F32)d_in[26];
  const int* git = (const int*)d_in[27];
  float* ws = (float*)d_ws;   // needs 85,968 B

  prep_weights<<<(W_TOTAL + 255) / 256, 256, 0, stream>>>(
      W2a, b2a, W2b, b2b, W2c, b2c, Wih, bih, Whh, bhh,
      W3a, b3a, W3b, b3b, W3c, b3c, W4, b4, W1a, b1a, ws);

  gnn_fused<<<BB, 256, 0, stream>>>(read_gru, gru_init, feat, edge_w, noise,
                                    xh, vp, git, ws, (float*)d_out);
}

// Round 3
// 1143.294 us; speedup vs baseline: 1.4381x; 1.4381x over previous
//
#include <hip/hip_runtime.h>
#include <hip/hip_bf16.h>

#define BB 1024
#define NN 32
#define SUD 8
#define HD 64
#define NCD 4
#define ED 992      // NN*(NN-1)
#define NITER 5

// ---- fp32 weight workspace layout (element offsets into d_ws) ----
#define O_W2AT 0        // 18 x 64   W2aT[su][f] = W2a[f][su]
#define O_B2A  1152     // 64
#define O_W2B  1216     // 32 x 64   row-major as given
#define O_B2B  3264     // 32
#define O_W2CT 3296     // 32 x 8    W2cT[o][su] = W2c[su][o]
#define O_B2C  3552     // 8
#define O_WIHT 3560     // 10 x 192  WihT[k][o]
#define O_BIH  5480     // 192
#define O_WHHT 5672     // 64 x 192  WhhT[k][o]
#define O_BHH  17960    // 192
#define O_W4T  18152    // 64 x 8    W4T[k][su]
#define O_B4   18664    // 8
#define O_W3AT 18672    // 8 x 64    W3aT[k][f]
#define O_B3A  19184    // 64
#define O_W3BT 19248    // 64 x 32   W3bT[k][f]
#define O_B3B  21296    // 32
#define O_W3CT 21328    // 32 x 4    W3cT[k][c]
#define O_B3C  21456    // 4
#define O_W1AT 21460    // 3 x 8     W1aT[c][su]
#define O_B1A  21484    // 8
#define W_TOTAL 21492   // floats (= 85,968 bytes in d_ws)

typedef const float* fwp;

// Transpose all weights into the layouts the main kernel wants. One elem/thread.
__global__ void prep_weights(fwp W2a, fwp b2a, fwp W2b, fwp b2b, fwp W2c, fwp b2c,
                             fwp Wih, fwp bih, fwp Whh, fwp bhh,
                             fwp W3a, fwp b3a, fwp W3b, fwp b3b, fwp W3c, fwp b3c,
                             fwp W4, fwp b4, fwp W1a, fwp b1a, float* __restrict__ ws) {
  int idx = blockIdx.x * 256 + threadIdx.x;
  if (idx >= W_TOTAL) return;
  float v;
  if (idx < O_B2A)       { int p = idx;          int su = p / 64, f = p % 64;   v = W2a[f * 18 + su]; }
  else if (idx < O_W2B)  { v = b2a[idx - O_B2A]; }
  else if (idx < O_B2B)  { v = W2b[idx - O_W2B]; }
  else if (idx < O_W2CT) { v = b2b[idx - O_B2B]; }
  else if (idx < O_B2C)  { int p = idx - O_W2CT; int o = p / 8, su = p % 8;     v = W2c[su * 32 + o]; }
  else if (idx < O_WIHT) { v = b2c[idx - O_B2C]; }
  else if (idx < O_BIH)  { int p = idx - O_WIHT; int k = p / 192, o = p % 192;  v = Wih[o * 10 + k]; }
  else if (idx < O_WHHT) { v = bih[idx - O_BIH]; }
  else if (idx < O_BHH)  { int p = idx - O_WHHT; int k = p / 192, o = p % 192;  v = Whh[o * 64 + k]; }
  else if (idx < O_W4T)  { v = bhh[idx - O_BHH]; }
  else if (idx < O_B4)   { int p = idx - O_W4T;  int k = p / 8, su = p % 8;     v = W4[su * 64 + k]; }
  else if (idx < O_W3AT) { v = b4[idx - O_B4]; }
  else if (idx < O_B3A)  { int p = idx - O_W3AT; int k = p / 64, f = p % 64;    v = W3a[f * 8 + k]; }
  else if (idx < O_W3BT) { v = b3a[idx - O_B3A]; }
  else if (idx < O_B3B)  { int p = idx - O_W3BT; int k = p / 32, f = p % 32;    v = W3b[f * 64 + k]; }
  else if (idx < O_W3CT) { v = b3b[idx - O_B3B]; }
  else if (idx < O_B3C)  { int p = idx - O_W3CT; int k = p / 4, c = p % 4;      v = W3c[c * 32 + k]; }
  else if (idx < O_W1AT) { v = b3c[idx - O_B3C]; }
  else if (idx < O_B1A)  { int p = idx - O_W1AT; int c = p / 8, su = p % 8;     v = W1a[su * 3 + c]; }
  else                   { v = b1a[idx - O_B1A]; }
  ws[idx] = v;
}

// One block per batch sample. Entire 5-iteration recurrence lives in LDS/regs.
// launch_bounds(256,2): 256-VGPR budget so m1[64] stays in registers (the
// (256,3)=170-reg cap made the allocator spill m1 to scratch -> 2.4 GB HBM).
__global__ __launch_bounds__(256, 2) void gnn_fused(
    const float* __restrict__ read_gru_in,
    const float* __restrict__ gru_init,
    const float* __restrict__ feat,
    const float* __restrict__ edge_w,
    const float* __restrict__ noise_in,
    const float* __restrict__ xhat,
    const float* __restrict__ vep,
    const int* __restrict__ gnn_iter_p,
    const float* __restrict__ ws,
    float* __restrict__ out)
{
  __shared__ float  sA1[NN * 65];    // A1[n][f]   (pad 65: conflict-free)
  __shared__ float  sA2[NN * 65];    // A2[n][f]
  __shared__ float  sH [NN * 65];    // gru_hidden[n][k]
  __shared__ float  sNodes[NN * 9];  // init_nodes / read_gru [n][su]
  __shared__ float  sSum[NN * 8];    // sum_msgs[n][su]
  __shared__ float  sPart[256 * 9];  // per-thread partial sums (pad 9)
  __shared__ float  sEw[ED];         // per-sample edge weights
  __shared__ float2 sCW[64];         // (c1[f] = b2a+noise*W2a[:,17], wew[f] = W2a[:,16])
  __shared__ float  sX[NN];
  __shared__ float  sV[NN];

  const int b = blockIdx.x;
  const int t = threadIdx.x;

  // ---- load per-sample inputs ----
  float noi = noise_in[b];
  for (int e = t; e < ED; e += 256) sEw[e] = edge_w[b * ED + e];
  if (t < NN) { sX[t] = xhat[b * NN + t]; sV[t] = vep[b * NN + t]; }
  if (t < 64) {
    float c1 = ws[O_B2A + t] + noi * ws[O_W2AT + 17 * 64 + t];
    float wewf = ws[O_W2AT + 16 * 64 + t];
    sCW[t] = make_float2(c1, wewf);
  }
#pragma unroll
  for (int i = 0; i < 8; ++i) {
    int p = t + 256 * i;
    sH[(p >> 6) * 65 + (p & 63)] = gru_init[b * (NN * HD) + p];
  }
  const int git = gnn_iter_p[0];

  for (int it = 0; it < NITER; ++it) {
    // ---- init_nodes ----
    if (it == 0) {
      int n = t >> 3, su = t & 7;
      float acc;
      if (git == 0) {
        acc = ws[O_B1A + su];
#pragma unroll
        for (int c = 0; c < 3; ++c)
          acc += ws[O_W1AT + c * 8 + su] * feat[b * (NN * 3) + n * 3 + c];
      } else {
        acc = read_gru_in[b * (NN * SUD) + t];
      }
      sNodes[n * 9 + su] = acc;
    }
    __syncthreads();

    // ---- A1[n] = W2a[:,0:8] @ nodes[n],  A2[n] = W2a[:,8:16] @ nodes[n] ----
#pragma unroll
    for (int i = 0; i < 8; ++i) {
      int p = t + 256 * i;
      int n = p >> 6, f = p & 63;            // n is wave-uniform, f = lane
      float a1 = 0.f, a2 = 0.f;
#pragma unroll
      for (int su = 0; su < 8; ++su) {
        float nv = sNodes[n * 9 + su];       // LDS broadcast
        a1 += ws[O_W2AT + su * 64 + f] * nv; // coalesced fp32
        a2 += ws[O_W2AT + (8 + su) * 64 + f] * nv;
      }
      sA1[n * 65 + f] = a1;
      sA2[n * 65 + f] = a2;
    }
    __syncthreads();

    // ---- edge MLP, fused layers b+c, per-thread edges ----
    {
      int jj = t >> 3, ii = t & 7;           // dest node jj, sub-lane ii
      float msum[8];
#pragma unroll
      for (int s = 0; s < 8; ++s) msum[s] = 0.f;
      for (int k = ii; k < 31; k += 8) {
        int a = k + (k >= jj ? 1 : 0);       // temp_a index
        float ewv = sEw[jj * 31 + k];
        float m1[64];
#pragma unroll
        for (int f = 0; f < 64; ++f) {
          float2 cw = sCW[f];                // broadcast b64
          float v = sA1[a * 65 + f] + sA2[jj * 65 + f] + cw.x + ewv * cw.y;
          m1[f] = v > 0.f ? v : 0.f;
        }
        float m3[8];
#pragma unroll
        for (int s = 0; s < 8; ++s) m3[s] = ws[O_B2C + s];
        for (int o = 0; o < 32; ++o) {       // wave-uniform -> scalar loads
          const float* wrow = ws + O_W2B + o * 64;
          float c0 = 0.f, c1v = 0.f, c2 = 0.f, c3 = 0.f;
#pragma unroll
          for (int k2 = 0; k2 < 64; k2 += 4) {
            c0  += wrow[k2 + 0] * m1[k2 + 0];
            c1v += wrow[k2 + 1] * m1[k2 + 1];
            c2  += wrow[k2 + 2] * m1[k2 + 2];
            c3  += wrow[k2 + 3] * m1[k2 + 3];
          }
          float acc = ws[O_B2B + o] + ((c0 + c1v) + (c2 + c3));
          acc = acc > 0.f ? acc : 0.f;       // relu layer b
          const float* crow = ws + O_W2CT + o * 8;
#pragma unroll
          for (int s = 0; s < 8; ++s) m3[s] += crow[s] * acc;  // fused layer c
        }
#pragma unroll
        for (int s = 0; s < 8; ++s) { float v = m3[s]; msum[s] += (v > 0.f ? v : 0.f); } // relu layer c
      }
#pragma unroll
      for (int s = 0; s < 8; ++s) sPart[t * 9 + s] = msum[s];
    }
    __syncthreads();

    // ---- reduce 8 partials per node -> sum_msgs ----
    {
      int n = t >> 3, su = t & 7;
      float acc = 0.f;
#pragma unroll
      for (int i = 0; i < 8; ++i) acc += sPart[(n * 8 + i) * 9 + su];
      sSum[n * 8 + su] = acc;
    }
    __syncthreads();

    // ---- GRU: lane owns gate-column oo for 8 nodes ----
    {
      int oo = t & 63, wq = t >> 6;
      float ar[8], az[8], inx[8], hn[8];
      {
        float br  = ws[O_BIH + oo]        + ws[O_BHH + oo];
        float bz  = ws[O_BIH + 64 + oo]   + ws[O_BHH + 64 + oo];
        float bni = ws[O_BIH + 128 + oo];
        float bnh = ws[O_BHH + 128 + oo];
#pragma unroll
        for (int j = 0; j < 8; ++j) { ar[j] = br; az[j] = bz; inx[j] = bni; hn[j] = bnh; }
      }
#pragma unroll
      for (int k = 0; k < 8; ++k) {          // gi over sum_msgs
        float wr = ws[O_WIHT + k * 192 + oo];
        float wz = ws[O_WIHT + k * 192 + 64 + oo];
        float wn = ws[O_WIHT + k * 192 + 128 + oo];
#pragma unroll
        for (int j = 0; j < 8; ++j) {
          float g = sSum[(wq + 4 * j) * 8 + k];
          ar[j] += wr * g; az[j] += wz * g; inx[j] += wn * g;
        }
      }
      {                                      // gi over x_hat (k=8) and var (k=9)
        float wr = ws[O_WIHT + 8 * 192 + oo];
        float wz = ws[O_WIHT + 8 * 192 + 64 + oo];
        float wn = ws[O_WIHT + 8 * 192 + 128 + oo];
#pragma unroll
        for (int j = 0; j < 8; ++j) {
          float g = sX[wq + 4 * j];
          ar[j] += wr * g; az[j] += wz * g; inx[j] += wn * g;
        }
        wr = ws[O_WIHT + 9 * 192 + oo];
        wz = ws[O_WIHT + 9 * 192 + 64 + oo];
        wn = ws[O_WIHT + 9 * 192 + 128 + oo];
#pragma unroll
        for (int j = 0; j < 8; ++j) {
          float g = sV[wq + 4 * j];
          ar[j] += wr * g; az[j] += wz * g; inx[j] += wn * g;
        }
      }
#pragma unroll 4
      for (int k = 0; k < 64; ++k) {         // gh over hidden
        float wr = ws[O_WHHT + k * 192 + oo];
        float wz = ws[O_WHHT + k * 192 + 64 + oo];
        float wn = ws[O_WHHT + k * 192 + 128 + oo];
#pragma unroll
        for (int j = 0; j < 8; ++j) {
          float hk = sH[(wq + 4 * j) * 65 + k];  // broadcast
          ar[j] += wr * hk; az[j] += wz * hk; hn[j] += wn * hk;
        }
      }
      float hnew[8];
#pragma unroll
      for (int j = 0; j < 8; ++j) {
        int n = wq + 4 * j;
        float r = 1.f / (1.f + __expf(-ar[j]));
        float z = 1.f / (1.f + __expf(-az[j]));
        float cd = inx[j] + r * hn[j];
        float e2 = __expf(2.f * cd);
        float th = 1.f - 2.f / (e2 + 1.f);   // tanh(cd)
        hnew[j] = (1.f - z) * th + z * sH[n * 65 + oo];
      }
      __syncthreads();                        // all old-h reads done
#pragma unroll
      for (int j = 0; j < 8; ++j) sH[(wq + 4 * j) * 65 + oo] = hnew[j];
    }
    __syncthreads();

    // ---- read_gru = W4 @ h + b4 -> sNodes (next iter's init_nodes) ----
    {
      int n = t >> 3, su = t & 7;
      float c0 = 0.f, c1v = 0.f, c2 = 0.f, c3 = 0.f;
#pragma unroll
      for (int k = 0; k < 64; k += 4) {
        c0  += ws[O_W4T + (k + 0) * 8 + su] * sH[n * 65 + k + 0];
        c1v += ws[O_W4T + (k + 1) * 8 + su] * sH[n * 65 + k + 1];
        c2  += ws[O_W4T + (k + 2) * 8 + su] * sH[n * 65 + k + 2];
        c3  += ws[O_W4T + (k + 3) * 8 + su] * sH[n * 65 + k + 3];
      }
      sNodes[n * 9 + su] = ws[O_B4 + su] + ((c0 + c1v) + (c2 + c3));
    }
    __syncthreads();
  } // iterations

  // ---- head: q1 = read @ W3aT + b3a (32x64) -> reuse sA1 ----
#pragma unroll
  for (int i = 0; i < 8; ++i) {
    int p = t + 256 * i;
    int n = p >> 6, f = p & 63;
    float acc = ws[O_B3A + f];
#pragma unroll
    for (int k = 0; k < 8; ++k) acc += ws[O_W3AT + k * 64 + f] * sNodes[n * 9 + k];
    sA1[n * 65 + f] = acc;
  }
  __syncthreads();
  // q2 (32x32) -> reuse sA2 at stride 33
#pragma unroll
  for (int i = 0; i < 4; ++i) {
    int p = t + 256 * i;
    int n = p >> 5, f = p & 31;
    float c0 = 0.f, c1v = 0.f, c2 = 0.f, c3 = 0.f;
#pragma unroll
    for (int k = 0; k < 64; k += 4) {
      c0  += ws[O_W3BT + (k + 0) * 32 + f] * sA1[n * 65 + k + 0];
      c1v += ws[O_W3BT + (k + 1) * 32 + f] * sA1[n * 65 + k + 1];
      c2  += ws[O_W3BT + (k + 2) * 32 + f] * sA1[n * 65 + k + 2];
      c3  += ws[O_W3BT + (k + 3) * 32 + f] * sA1[n * 65 + k + 3];
    }
    sA2[n * 33 + f] = ws[O_B3B + f] + ((c0 + c1v) + (c2 + c3));
  }
  __syncthreads();
  // p_y_x (32x4) + store
  if (t < 128) {
    int n = t >> 2, c = t & 3;
    float acc = ws[O_B3C + c];
#pragma unroll
    for (int k = 0; k < 32; ++k) acc += ws[O_W3CT + k * 4 + c] * sA2[n * 33 + k];
    out[b * (NN * NCD) + t] = acc;
  }
  // read_gru out
  out[BB * NN * NCD + b * (NN * SUD) + t] = sNodes[(t >> 3) * 9 + (t & 7)];
  // gru_hidden out
#pragma unroll
  for (int i = 0; i < 8; ++i) {
    int p = t + 256 * i;
    out[BB * NN * NCD + BB * NN * SUD + b * (NN * HD) + p] =
        sH[(p >> 6) * 65 + (p & 63)];
  }
}

extern "C" void kernel_launch(void* const* d_in, const int* in_sizes, int n_in,
                              void* d_out, int out_size, void* d_ws, size_t ws_size,
                              hipStream_t stream) {
  typedef const float* F32;
  F32 read_gru = (F32)d_in[0];
  F32 gru_init = (F32)d_in[1];
  F32 feat     = (F32)d_in[2];
  F32 edge_w   = (F32)d_in[3];
  F32 noise    = (F32)d_in[4];
  F32 xh       = (F32)d_in[5];
  F32 vp       = (F32)d_in[6];
  F32 W1a = (F32)d_in[7];  F32 b1a = (F32)d_in[8];
  F32 W2a = (F32)d_in[9];  F32 b2a = (F32)d_in[10];
  F32 W2b = (F32)d_in[11]; F32 b2b = (F32)d_in[12];
  F32 W2c = (F32)d_in[13]; F32 b2c = (F32)d_in[14];
  F32 Wih = (F32)d_in[15]; F32 bih = (F32)d_in[16];
  F32 Whh = (F32)d_in[17]; F32 bhh = (F32)d_in[18];
  F32 W3a = (F32)d_in[19]; F32 b3a = (F32)d_in[20];
  F32 W3b = (F32)d_in[21]; F32 b3b = (F32)d_in[22];
  F32 W3c = (F32)d_in[23]; F32 b3c = (F32)d_in[24];
  F32 W4  = (F32)d_in[25]; F32 b4  = (F32)d_in[26];
  const int* git = (const int*)d_in[27];
  float* ws = (float*)d_ws;   // needs 85,968 B

  prep_weights<<<(W_TOTAL + 255) / 256, 256, 0, stream>>>(
      W2a, b2a, W2b, b2b, W2c, b2c, Wih, bih, Whh, bhh,
      W3a, b3a, W3b, b3b, W3c, b3c, W4, b4, W1a, b1a, ws);

  gnn_fused<<<BB, 256, 0, stream>>>(read_gru, gru_init, feat, edge_w, noise,
                                    xh, vp, git, ws, (float*)d_out);
}